// Round 2
// baseline (3655.130 us; speedup 1.0000x reference)
//
#include <hip/hip_runtime.h>
#include <math.h>

#define BD   256    // D
#define NH   8      // heads
#define DH   32     // head dim
#define NB   16     // batch
#define NN   1024   // N
#define LQ   1025   // N+1
#define EPSV 1e-5f

// ---------------- copy helpers ----------------
__global__ void k_copy(const float* __restrict__ in, float* __restrict__ out, long n) {
  long stride = (long)gridDim.x * 256;
  for (long i = (long)blockIdx.x * 256 + threadIdx.x; i < n; i += stride)
    out[i] = in[i];
}

__global__ void k_copy_sat_to_x(const float* __restrict__ tmp, float* __restrict__ X) {
  long n = (long)NB * NN * BD;
  long stride = (long)gridDim.x * 256;
  for (long i = (long)blockIdx.x * 256 + threadIdx.x; i < n; i += stride) {
    long b = i / ((long)NN * BD);
    long r = i - b * ((long)NN * BD);
    X[b * (long)LQ * BD + BD + r] = tmp[i];
  }
}

__global__ void k_sat_out(const float* __restrict__ X, float* __restrict__ out) {
  long n = (long)NB * NN * BD;
  long stride = (long)gridDim.x * 256;
  for (long i = (long)blockIdx.x * 256 + threadIdx.x; i < n; i += stride) {
    long b = i / ((long)NN * BD);
    long r = i - b * ((long)NN * BD);
    out[i] = X[b * (long)LQ * BD + BD + r];
  }
}

// ---------------- GEMM: C[M,256] = A[M,256] @ W[256,256] ----------------
__global__ __launch_bounds__(256) void gemm_aw(const float* __restrict__ A,
                                               const float* __restrict__ W,
                                               float* __restrict__ C,
                                               int M, long strideA, long strideC) {
  A += (long)blockIdx.z * strideA;
  C += (long)blockIdx.z * strideC;
  __shared__ float As[16][65];  // [k][m]
  __shared__ float Ws[16][65];  // [k][n]
  int tid = threadIdx.x;
  int tx = tid & 15, ty = tid >> 4;
  int m0 = blockIdx.x * 64, n0 = blockIdx.y * 64;
  float acc[4][4] = {};
  for (int k0 = 0; k0 < 256; k0 += 16) {
    {
      int kk = tid & 15, mm = tid >> 4;  // 16x16, loop 4 over m
      #pragma unroll
      for (int r = 0; r < 4; r++) {
        int m = m0 + mm + r * 16;
        As[kk][mm + r * 16] = (m < M) ? A[(long)m * 256 + k0 + kk] : 0.f;
      }
    }
    {
      int nn = tid & 63, kk = tid >> 6;  // 4x64, loop 4 over k
      #pragma unroll
      for (int r = 0; r < 4; r++)
        Ws[kk + r * 4][nn] = W[(long)(k0 + kk + r * 4) * 256 + n0 + nn];
    }
    __syncthreads();
    #pragma unroll
    for (int kk = 0; kk < 16; kk++) {
      float a[4], w[4];
      #pragma unroll
      for (int i = 0; i < 4; i++) a[i] = As[kk][ty * 4 + i];
      #pragma unroll
      for (int j = 0; j < 4; j++) w[j] = Ws[kk][tx * 4 + j];
      #pragma unroll
      for (int i = 0; i < 4; i++)
        #pragma unroll
        for (int j = 0; j < 4; j++) acc[i][j] += a[i] * w[j];
    }
    __syncthreads();
  }
  #pragma unroll
  for (int i = 0; i < 4; i++) {
    int m = m0 + ty * 4 + i;
    if (m < M)
      #pragma unroll
      for (int j = 0; j < 4; j++)
        C[(long)m * 256 + n0 + tx * 4 + j] = acc[i][j];
  }
}

// ---------------- graph mixing: C[b,m,d] = sum_n G[b,n,m] * Xsat[b,n,d] ----------------
__global__ __launch_bounds__(256) void gemm_gtx(const float* __restrict__ G,
                                                const float* __restrict__ X,
                                                float* __restrict__ C) {
  int b = blockIdx.z;
  const float* Gb = G + (long)b * NN * NN;
  const float* Xs = X + (long)b * LQ * BD + BD;
  float* Cb = C + (long)b * NN * BD;
  __shared__ float As[16][65];  // [k=n][m]
  __shared__ float Bs[16][65];  // [k=n][d]
  int tid = threadIdx.x;
  int tx = tid & 15, ty = tid >> 4;
  int m0 = blockIdx.x * 64, n0 = blockIdx.y * 64;
  float acc[4][4] = {};
  for (int k0 = 0; k0 < NN; k0 += 16) {
    int mm = tid & 63, kk = tid >> 6;
    #pragma unroll
    for (int r = 0; r < 4; r++)
      As[kk + r * 4][mm] = Gb[(long)(k0 + kk + r * 4) * NN + m0 + mm];
    #pragma unroll
    for (int r = 0; r < 4; r++)
      Bs[kk + r * 4][mm] = Xs[(long)(k0 + kk + r * 4) * BD + n0 + mm];
    __syncthreads();
    #pragma unroll
    for (int kk2 = 0; kk2 < 16; kk2++) {
      float a[4], w[4];
      #pragma unroll
      for (int i = 0; i < 4; i++) a[i] = As[kk2][ty * 4 + i];
      #pragma unroll
      for (int j = 0; j < 4; j++) w[j] = Bs[kk2][tx * 4 + j];
      #pragma unroll
      for (int i = 0; i < 4; i++)
        #pragma unroll
        for (int j = 0; j < 4; j++) acc[i][j] += a[i] * w[j];
    }
    __syncthreads();
  }
  #pragma unroll
  for (int i = 0; i < 4; i++) {
    int m = m0 + ty * 4 + i;
    #pragma unroll
    for (int j = 0; j < 4; j++)
      Cb[(long)m * BD + n0 + tx * 4 + j] = acc[i][j];
  }
}

// ---------------- self attention, flash-style online softmax ----------------
// block = 256 threads = 8 q-rows x 32 lanes; grid (129, NH, NB)
__global__ __launch_bounds__(256) void attn_self(const float* __restrict__ Q,
                                                 const float* __restrict__ K,
                                                 const float* __restrict__ V,
                                                 float* __restrict__ O) {
  const int TQ = 8, KC = 32;
  const float scale = 0.17677669529663687f;  // 1/sqrt(32)
  int q0 = blockIdx.x * TQ, h = blockIdx.y, b = blockIdx.z;
  int tid = threadIdx.x;
  int lane = tid & 31, qq = tid >> 5;
  long base = ((long)b * LQ) * BD + h * DH;
  __shared__ float qs[TQ][DH];
  __shared__ float kv[KC][DH + 1];
  __shared__ float vv[KC][DH + 1];
  __shared__ float ps[TQ][KC + 1];
  float m_run = -1e30f, l_run = 0.f, oacc = 0.f;

  for (int i = tid; i < TQ * DH; i += 256) {
    int r = i >> 5, d = i & 31;
    int qrow = q0 + r;
    qs[r][d] = (qrow < LQ) ? Q[base + (long)qrow * BD + d] : 0.f;
  }
  __syncthreads();

  for (int k0 = 0; k0 < LQ; k0 += KC) {
    for (int i = tid; i < KC * DH; i += 256) {
      int r = i >> 5, d = i & 31;
      int k = k0 + r;
      if (k < LQ) {
        kv[r][d] = K[base + (long)k * BD + d];
        vv[r][d] = V[base + (long)k * BD + d];
      } else {
        kv[r][d] = 0.f;
        vv[r][d] = 0.f;
      }
    }
    __syncthreads();
    // scores: thread = (qq, k-lane)
    float dot = 0.f;
    #pragma unroll
    for (int d = 0; d < DH; d++) dot += qs[qq][d] * kv[lane][d];
    float sc = (k0 + lane < LQ) ? dot * scale : -1e30f;
    float cm = sc;
    #pragma unroll
    for (int off = 16; off > 0; off >>= 1) cm = fmaxf(cm, __shfl_xor(cm, off, 32));
    float m_new = fmaxf(m_run, cm);
    float p = (k0 + lane < LQ) ? __expf(sc - m_new) : 0.f;
    float psum = p;
    #pragma unroll
    for (int off = 16; off > 0; off >>= 1) psum += __shfl_xor(psum, off, 32);
    float alpha = __expf(m_run - m_new);
    l_run = l_run * alpha + psum;
    m_run = m_new;
    ps[qq][lane] = p;
    __syncthreads();
    // PV: thread = (qq, d-lane)
    float part = 0.f;
    #pragma unroll
    for (int r = 0; r < KC; r++) part += ps[qq][r] * vv[r][lane];
    oacc = oacc * alpha + part;
    __syncthreads();
  }
  int qrow = q0 + qq;
  if (qrow < LQ) O[base + (long)qrow * BD + lane] = oacc / l_run;
}

// ---------------- relay attention: Lq=1, Lk=1024, per (batch, head) ----------------
__global__ __launch_bounds__(256) void attn_relay(const float* __restrict__ q,
                                                  const float* __restrict__ K,
                                                  const float* __restrict__ V,
                                                  float* __restrict__ o) {
  int b = blockIdx.x, h = blockIdx.y;
  int tid = threadIdx.x;
  const float scale = 0.17677669529663687f;
  __shared__ float s[NN];
  __shared__ float qs[DH];
  __shared__ float rbuf[256];
  __shared__ float part[8][33];
  if (tid < DH) qs[tid] = q[(long)b * BD + h * DH + tid];
  __syncthreads();
  long base = ((long)b * NN) * BD + h * DH;
  for (int k = tid; k < NN; k += 256) {
    float dot = 0.f;
    #pragma unroll
    for (int d = 0; d < DH; d++) dot += qs[d] * K[base + (long)k * BD + d];
    s[k] = dot * scale;
  }
  __syncthreads();
  float m = -1e30f;
  for (int k = tid; k < NN; k += 256) m = fmaxf(m, s[k]);
  rbuf[tid] = m;
  __syncthreads();
  for (int st = 128; st > 0; st >>= 1) {
    if (tid < st) rbuf[tid] = fmaxf(rbuf[tid], rbuf[tid + st]);
    __syncthreads();
  }
  float mx = rbuf[0];
  __syncthreads();
  float sm = 0.f;
  for (int k = tid; k < NN; k += 256) {
    float p = __expf(s[k] - mx);
    s[k] = p;
    sm += p;
  }
  rbuf[tid] = sm;
  __syncthreads();
  for (int st = 128; st > 0; st >>= 1) {
    if (tid < st) rbuf[tid] += rbuf[tid + st];
    __syncthreads();
  }
  float inv = 1.f / rbuf[0];
  int d = tid & 31, slice = tid >> 5;
  float acc = 0.f;
  for (int k = slice; k < NN; k += 8) acc += s[k] * V[base + (long)k * BD + d];
  part[slice][d] = acc;
  __syncthreads();
  if (tid < DH) {
    float ss = 0.f;
    #pragma unroll
    for (int t = 0; t < 8; t++) ss += part[t][tid];
    o[(long)b * BD + h * DH + tid] = ss * inv;
  }
}

// ---------------- relay row ops ----------------
__global__ __launch_bounds__(256) void rowvec_matmul(const float* __restrict__ X, long xstride,
                                                     const float* __restrict__ W,
                                                     float* __restrict__ out) {
  int b = blockIdx.x, tid = threadIdx.x;
  __shared__ float xs[BD];
  xs[tid] = X[(long)b * xstride + tid];
  __syncthreads();
  float acc = 0.f;
  for (int k = 0; k < BD; k++) acc += xs[k] * W[(long)k * BD + tid];
  out[(long)b * BD + tid] = acc;
}

__global__ __launch_bounds__(256) void rowvec_oproj_ln(const float* __restrict__ o,
                                                       const float* __restrict__ Wo,
                                                       const float* __restrict__ Xres, long xstride,
                                                       const float* __restrict__ g,
                                                       const float* __restrict__ beta,
                                                       float* __restrict__ dst, long dstride) {
  int b = blockIdx.x, tid = threadIdx.x;
  __shared__ float xs[BD];
  __shared__ float rs[256], rq[256];
  xs[tid] = o[(long)b * BD + tid];
  __syncthreads();
  float acc = 0.f;
  for (int k = 0; k < BD; k++) acc += xs[k] * Wo[(long)k * BD + tid];
  float v = acc + Xres[(long)b * xstride + tid];
  rs[tid] = v;
  rq[tid] = v * v;
  __syncthreads();
  for (int st = 128; st > 0; st >>= 1) {
    if (tid < st) { rs[tid] += rs[tid + st]; rq[tid] += rq[tid + st]; }
    __syncthreads();
  }
  float mu = rs[0] * (1.f / BD);
  float var = rq[0] * (1.f / BD) - mu * mu;
  float y = (v - mu) * rsqrtf(var + EPSV) * g[tid] + beta[tid];
  dst[(long)b * dstride + tid] = y;
}

__global__ __launch_bounds__(256) void ln_residual(const float* __restrict__ OP,
                                                   float* __restrict__ X,
                                                   const float* __restrict__ g,
                                                   const float* __restrict__ beta) {
  long r = blockIdx.x;
  int tid = threadIdx.x;
  __shared__ float rs[256], rq[256];
  float v = OP[r * BD + tid] + X[r * BD + tid];
  rs[tid] = v;
  rq[tid] = v * v;
  __syncthreads();
  for (int st = 128; st > 0; st >>= 1) {
    if (tid < st) { rs[tid] += rs[tid + st]; rq[tid] += rq[tid + st]; }
    __syncthreads();
  }
  float mu = rs[0] * (1.f / BD);
  float var = rq[0] * (1.f / BD) - mu * mu;
  X[r * BD + tid] = (v - mu) * rsqrtf(var + EPSV) * g[tid] + beta[tid];
}

// ---------------- launch ----------------
extern "C" void kernel_launch(void* const* d_in, const int* in_sizes, int n_in,
                              void* d_out, int out_size, void* d_ws, size_t ws_size,
                              hipStream_t stream) {
  const float* gv    = (const float*)d_in[0];
  const float* graph = (const float*)d_in[1];
  const float* Wq    = (const float*)d_in[2];
  const float* Wk    = (const float*)d_in[3];
  const float* Wv    = (const float*)d_in[4];
  const float* Wo    = (const float*)d_in[5];
  const float* lg    = (const float*)d_in[6];
  const float* lb    = (const float*)d_in[7];
  float* out = (float*)d_out;

  float* ws = (float*)d_ws;
  const long S = (long)NB * LQ * BD;  // 4,198,400 floats
  float* X    = ws;
  float* Qb   = ws + S;
  float* Kb   = ws + 2 * S;
  float* Vb   = ws + 3 * S;
  float* Ob   = ws + 4 * S;
  float* qrel = ws + 5 * S;  // NB*256
  float* orel = qrel + (long)NB * BD;

  const long WSZ = (long)BD * BD;
  const long XST = (long)LQ * BD;
  dim3 blk(256);

  // X = graph_vectors (private copy; we mutate it)
  k_copy<<<dim3(2048), blk, 0, stream>>>(gv, X, S);

  // ---- layer 0: relay GAT (q from relay row, k/v from sat) ----
  rowvec_matmul<<<dim3(NB), blk, 0, stream>>>(X, XST, Wq + 0 * WSZ, qrel);
  gemm_aw<<<dim3(16, 4, NB), blk, 0, stream>>>(X + BD, Wk + 0 * WSZ, Kb, NN, XST, (long)NN * BD);
  gemm_aw<<<dim3(16, 4, NB), blk, 0, stream>>>(X + BD, Wv + 0 * WSZ, Vb, NN, XST, (long)NN * BD);
  attn_relay<<<dim3(NB, NH), blk, 0, stream>>>(qrel, Kb, Vb, orel);
  rowvec_oproj_ln<<<dim3(NB), blk, 0, stream>>>(orel, Wo + 0 * WSZ, X, XST,
                                                lg + 0 * BD, lb + 0 * BD, X, XST);

  // ---- sat mixing: sat = G^T @ sat ----
  gemm_gtx<<<dim3(16, 4, NB), blk, 0, stream>>>(graph, X, Qb);
  k_copy_sat_to_x<<<dim3(2048), blk, 0, stream>>>(Qb, X);

  // ---- layers 1,2: self GAT over all 1025 tokens ----
  for (int l = 1; l <= 2; l++) {
    gemm_aw<<<dim3(257, 4, 1), blk, 0, stream>>>(X, Wq + l * WSZ, Qb, NB * LQ, 0, 0);
    gemm_aw<<<dim3(257, 4, 1), blk, 0, stream>>>(X, Wk + l * WSZ, Kb, NB * LQ, 0, 0);
    gemm_aw<<<dim3(257, 4, 1), blk, 0, stream>>>(X, Wv + l * WSZ, Vb, NB * LQ, 0, 0);
    attn_self<<<dim3(129, NH, NB), blk, 0, stream>>>(Qb, Kb, Vb, Ob);
    gemm_aw<<<dim3(257, 4, 1), blk, 0, stream>>>(Ob, Wo + l * WSZ, Qb, NB * LQ, 0, 0);
    ln_residual<<<dim3(NB * LQ), blk, 0, stream>>>(Qb, X, lg + l * BD, lb + l * BD);
  }

  // ---- sat_u output (X sat region, pre-final-layer) ----
  k_sat_out<<<dim3(2048), blk, 0, stream>>>(X, out + (long)NB * BD);

  // ---- layer 3: final relay GAT -> z ----
  rowvec_matmul<<<dim3(NB), blk, 0, stream>>>(X, XST, Wq + 3 * WSZ, qrel);
  gemm_aw<<<dim3(16, 4, NB), blk, 0, stream>>>(X + BD, Wk + 3 * WSZ, Kb, NN, XST, (long)NN * BD);
  gemm_aw<<<dim3(16, 4, NB), blk, 0, stream>>>(X + BD, Wv + 3 * WSZ, Vb, NN, XST, (long)NN * BD);
  attn_relay<<<dim3(NB, NH), blk, 0, stream>>>(qrel, Kb, Vb, orel);
  rowvec_oproj_ln<<<dim3(NB), blk, 0, stream>>>(orel, Wo + 3 * WSZ, X, XST,
                                                lg + 3 * BD, lb + 3 * BD, out, BD);
}

// Round 4
// 1372.857 us; speedup vs baseline: 2.6624x; 2.6624x over previous
//
#include <hip/hip_runtime.h>
#include <hip/hip_bf16.h>
#include <math.h>

#define BD   256    // D
#define NH   8      // heads
#define DH   32     // head dim
#define NB   16     // batch
#define NN   1024   // N
#define LQ   1025   // N+1
#define EPSV 1e-5f

typedef __attribute__((ext_vector_type(8))) short short8;
typedef __attribute__((ext_vector_type(4))) float f32x4;

static __device__ __forceinline__ unsigned short f2b(float x) {
  union { __hip_bfloat16 h; unsigned short u; } cv;
  cv.h = __float2bfloat16(x);
  return cv.u;
}

// ---------------- copy helpers ----------------
__global__ void k_copy(const float* __restrict__ in, float* __restrict__ out, long n) {
  long stride = (long)gridDim.x * 256;
  for (long i = (long)blockIdx.x * 256 + threadIdx.x; i < n; i += stride)
    out[i] = in[i];
}

__global__ void k_copy_sat_to_x(const float* __restrict__ tmp, float* __restrict__ X) {
  long n = (long)NB * NN * BD;
  long stride = (long)gridDim.x * 256;
  for (long i = (long)blockIdx.x * 256 + threadIdx.x; i < n; i += stride) {
    long b = i / ((long)NN * BD);
    long r = i - b * ((long)NN * BD);
    X[b * (long)LQ * BD + BD + r] = tmp[i];
  }
}

__global__ void k_sat_out(const float* __restrict__ X, float* __restrict__ out) {
  long n = (long)NB * NN * BD;
  long stride = (long)gridDim.x * 256;
  for (long i = (long)blockIdx.x * 256 + threadIdx.x; i < n; i += stride) {
    long b = i / ((long)NN * BD);
    long r = i - b * ((long)NN * BD);
    out[i] = X[b * (long)LQ * BD + BD + r];
  }
}

// ---------------- GEMM: C[M,256] = A[M,256] @ W[256,256], fp32 out ----------------
__global__ __launch_bounds__(256) void gemm_aw(const float* __restrict__ A,
                                               const float* __restrict__ W,
                                               float* __restrict__ C,
                                               int M, long strideA, long strideC) {
  A += (long)blockIdx.z * strideA;
  C += (long)blockIdx.z * strideC;
  __shared__ float As[16][65];
  __shared__ float Ws[16][65];
  int tid = threadIdx.x;
  int tx = tid & 15, ty = tid >> 4;
  int m0 = blockIdx.x * 64, n0 = blockIdx.y * 64;
  float acc[4][4] = {};
  for (int k0 = 0; k0 < 256; k0 += 16) {
    {
      int kk = tid & 15, mm = tid >> 4;
      #pragma unroll
      for (int r = 0; r < 4; r++) {
        int m = m0 + mm + r * 16;
        As[kk][mm + r * 16] = (m < M) ? A[(long)m * 256 + k0 + kk] : 0.f;
      }
    }
    {
      int nn = tid & 63, kk = tid >> 6;
      #pragma unroll
      for (int r = 0; r < 4; r++)
        Ws[kk + r * 4][nn] = W[(long)(k0 + kk + r * 4) * 256 + n0 + nn];
    }
    __syncthreads();
    #pragma unroll
    for (int kk = 0; kk < 16; kk++) {
      float a[4], w[4];
      #pragma unroll
      for (int i = 0; i < 4; i++) a[i] = As[kk][ty * 4 + i];
      #pragma unroll
      for (int j = 0; j < 4; j++) w[j] = Ws[kk][tx * 4 + j];
      #pragma unroll
      for (int i = 0; i < 4; i++)
        #pragma unroll
        for (int j = 0; j < 4; j++) acc[i][j] += a[i] * w[j];
    }
    __syncthreads();
  }
  #pragma unroll
  for (int i = 0; i < 4; i++) {
    int m = m0 + ty * 4 + i;
    if (m < M)
      #pragma unroll
      for (int j = 0; j < 4; j++)
        C[(long)m * 256 + n0 + tx * 4 + j] = acc[i][j];
  }
}

// ---------------- same GEMM but bf16 output (for Q/K/V feeding MFMA attention) ----------------
__global__ __launch_bounds__(256) void gemm_aw_h(const float* __restrict__ A,
                                                 const float* __restrict__ W,
                                                 unsigned short* __restrict__ C,
                                                 int M) {
  __shared__ float As[16][65];
  __shared__ float Ws[16][65];
  int tid = threadIdx.x;
  int tx = tid & 15, ty = tid >> 4;
  int m0 = blockIdx.x * 64, n0 = blockIdx.y * 64;
  float acc[4][4] = {};
  for (int k0 = 0; k0 < 256; k0 += 16) {
    {
      int kk = tid & 15, mm = tid >> 4;
      #pragma unroll
      for (int r = 0; r < 4; r++) {
        int m = m0 + mm + r * 16;
        As[kk][mm + r * 16] = (m < M) ? A[(long)m * 256 + k0 + kk] : 0.f;
      }
    }
    {
      int nn = tid & 63, kk = tid >> 6;
      #pragma unroll
      for (int r = 0; r < 4; r++)
        Ws[kk + r * 4][nn] = W[(long)(k0 + kk + r * 4) * 256 + n0 + nn];
    }
    __syncthreads();
    #pragma unroll
    for (int kk = 0; kk < 16; kk++) {
      float a[4], w[4];
      #pragma unroll
      for (int i = 0; i < 4; i++) a[i] = As[kk][ty * 4 + i];
      #pragma unroll
      for (int j = 0; j < 4; j++) w[j] = Ws[kk][tx * 4 + j];
      #pragma unroll
      for (int i = 0; i < 4; i++)
        #pragma unroll
        for (int j = 0; j < 4; j++) acc[i][j] += a[i] * w[j];
    }
    __syncthreads();
  }
  #pragma unroll
  for (int i = 0; i < 4; i++) {
    int m = m0 + ty * 4 + i;
    if (m < M)
      #pragma unroll
      for (int j = 0; j < 4; j++)
        C[(long)m * 256 + n0 + tx * 4 + j] = f2b(acc[i][j]);
  }
}

// ---------------- graph mixing: C[b,m,d] = sum_n G[b,n,m] * Xsat[b,n,d] ----------------
__global__ __launch_bounds__(256) void gemm_gtx(const float* __restrict__ G,
                                                const float* __restrict__ X,
                                                float* __restrict__ C) {
  int b = blockIdx.z;
  const float* Gb = G + (long)b * NN * NN;
  const float* Xs = X + (long)b * LQ * BD + BD;
  float* Cb = C + (long)b * NN * BD;
  __shared__ float As[16][65];
  __shared__ float Bs[16][65];
  int tid = threadIdx.x;
  int tx = tid & 15, ty = tid >> 4;
  int m0 = blockIdx.x * 64, n0 = blockIdx.y * 64;
  float acc[4][4] = {};
  for (int k0 = 0; k0 < NN; k0 += 16) {
    int mm = tid & 63, kk = tid >> 6;
    #pragma unroll
    for (int r = 0; r < 4; r++)
      As[kk + r * 4][mm] = Gb[(long)(k0 + kk + r * 4) * NN + m0 + mm];
    #pragma unroll
    for (int r = 0; r < 4; r++)
      Bs[kk + r * 4][mm] = Xs[(long)(k0 + kk + r * 4) * BD + n0 + mm];
    __syncthreads();
    #pragma unroll
    for (int kk2 = 0; kk2 < 16; kk2++) {
      float a[4], w[4];
      #pragma unroll
      for (int i = 0; i < 4; i++) a[i] = As[kk2][ty * 4 + i];
      #pragma unroll
      for (int j = 0; j < 4; j++) w[j] = Bs[kk2][tx * 4 + j];
      #pragma unroll
      for (int i = 0; i < 4; i++)
        #pragma unroll
        for (int j = 0; j < 4; j++) acc[i][j] += a[i] * w[j];
    }
    __syncthreads();
  }
  #pragma unroll
  for (int i = 0; i < 4; i++) {
    int m = m0 + ty * 4 + i;
    #pragma unroll
    for (int j = 0; j < 4; j++)
      Cb[(long)m * BD + n0 + tx * 4 + j] = acc[i][j];
  }
}

// ---------------- self attention via MFMA, bf16 inputs, ONLINE-MAX softmax ----------------
// grid (ceil(LQ/64)=17, NH, NB); block 256 = 4 waves, one 16-row q-tile per wave.
// Layer-1 scores reach |s| ~ 200 (un-normalized graph-mixed sat rows): max subtraction is
// mandatory. Per 32-key chunk: row max via 4 shfl_xor over the quad's 16 lanes, rescale
// o/l by alpha before the PV MFMA accumulates.
__global__ __launch_bounds__(256) void attn_mfma(const unsigned short* __restrict__ Qh,
                                                 const unsigned short* __restrict__ Kh,
                                                 const unsigned short* __restrict__ Vh,
                                                 float* __restrict__ O) {
  __shared__ __align__(16) unsigned short Ks[32][40];      // [k][d]
  __shared__ __align__(16) unsigned short Vt[32][40];      // [d][k] (transposed for B-frag)
  __shared__ __align__(16) unsigned short Ps[4][16][40];   // per-wave P round-trip
  const float scale = 0.17677669529663687f;  // 1/sqrt(32)
  int tid = threadIdx.x;
  int wave = tid >> 6, lane = tid & 63;
  int l15 = lane & 15, quad = lane >> 4;
  int h = blockIdx.y, b = blockIdx.z;
  long hb = ((long)b * LQ) * BD + h * DH;
  int q0 = blockIdx.x * 64 + wave * 16;
  int qc = q0 + l15; if (qc > LQ - 1) qc = LQ - 1;   // clamp tail reads in-bounds
  short8 qfrag = *(const short8*)&Qh[hb + (long)qc * BD + quad * 8];

  f32x4 o0 = {0.f, 0.f, 0.f, 0.f}, o1 = {0.f, 0.f, 0.f, 0.f};
  f32x4 lsum = {0.f, 0.f, 0.f, 0.f};
  f32x4 mrun = {-1e30f, -1e30f, -1e30f, -1e30f};

  int sr = tid >> 3;            // staging: key row 0..31
  int sd = (tid & 7) * 4;       // staging: dim 0,4,..,28

  for (int k0 = 0; k0 < LQ; k0 += 32) {
    int kk = k0 + sr;
    if (kk < LQ) {
      *(uint2*)&Ks[sr][sd] = *(const uint2*)&Kh[hb + (long)kk * BD + sd];
      const unsigned short* vp = &Vh[hb + (long)kk * BD + sd];
      Vt[sd][sr] = vp[0]; Vt[sd + 1][sr] = vp[1];
      Vt[sd + 2][sr] = vp[2]; Vt[sd + 3][sr] = vp[3];
    } else {
      uint2 z; z.x = 0; z.y = 0;
      *(uint2*)&Ks[sr][sd] = z;
      Vt[sd][sr] = 0; Vt[sd + 1][sr] = 0; Vt[sd + 2][sr] = 0; Vt[sd + 3][sr] = 0;
    }
    __syncthreads();
    short8 bk0 = *(const short8*)&Ks[l15][quad * 8];
    short8 bk1 = *(const short8*)&Ks[16 + l15][quad * 8];
    f32x4 z4 = {0.f, 0.f, 0.f, 0.f};
    f32x4 s0 = __builtin_amdgcn_mfma_f32_16x16x32_bf16(qfrag, bk0, z4, 0, 0, 0);
    f32x4 s1 = __builtin_amdgcn_mfma_f32_16x16x32_bf16(qfrag, bk1, z4, 0, 0, 0);
    bool v0 = (k0 + l15) < LQ;
    bool v1 = (k0 + 16 + l15) < LQ;
    #pragma unroll
    for (int r = 0; r < 4; r++) {
      float sc0 = v0 ? s0[r] * scale : -1e30f;
      float sc1 = v1 ? s1[r] * scale : -1e30f;
      float cm = fmaxf(sc0, sc1);
      cm = fmaxf(cm, __shfl_xor(cm, 1));
      cm = fmaxf(cm, __shfl_xor(cm, 2));
      cm = fmaxf(cm, __shfl_xor(cm, 4));
      cm = fmaxf(cm, __shfl_xor(cm, 8));
      float mn = fmaxf(mrun[r], cm);
      float alpha = __expf(mrun[r] - mn);   // first iter: exp(-inf) = 0
      mrun[r] = mn;
      float p0 = __expf(sc0 - mn);          // invalid cols -> exp(-inf) = 0
      float p1 = __expf(sc1 - mn);
      lsum[r] = lsum[r] * alpha + p0 + p1;
      o0[r] *= alpha; o1[r] *= alpha;
      Ps[wave][quad * 4 + r][l15] = f2b(p0);
      Ps[wave][quad * 4 + r][16 + l15] = f2b(p1);
    }
    short8 pf  = *(const short8*)&Ps[wave][l15][quad * 8];
    short8 vf0 = *(const short8*)&Vt[l15][quad * 8];
    short8 vf1 = *(const short8*)&Vt[16 + l15][quad * 8];
    o0 = __builtin_amdgcn_mfma_f32_16x16x32_bf16(pf, vf0, o0, 0, 0, 0);
    o1 = __builtin_amdgcn_mfma_f32_16x16x32_bf16(pf, vf1, o1, 0, 0, 0);
    __syncthreads();
  }
  #pragma unroll
  for (int r = 0; r < 4; r++) {
    float s = lsum[r];
    s += __shfl_xor(s, 1); s += __shfl_xor(s, 2);
    s += __shfl_xor(s, 4); s += __shfl_xor(s, 8);
    lsum[r] = s;
  }
  #pragma unroll
  for (int r = 0; r < 4; r++) {
    int row = q0 + quad * 4 + r;
    if (row < LQ) {
      float inv = 1.f / lsum[r];
      O[hb + (long)row * BD + l15] = o0[r] * inv;
      O[hb + (long)row * BD + 16 + l15] = o1[r] * inv;
    }
  }
}

// ---------------- relay attention: Lq=1, Lk=1024, per (batch, head) ----------------
__global__ __launch_bounds__(256) void attn_relay(const float* __restrict__ q,
                                                  const float* __restrict__ K,
                                                  const float* __restrict__ V,
                                                  float* __restrict__ o) {
  int b = blockIdx.x, h = blockIdx.y;
  int tid = threadIdx.x;
  const float scale = 0.17677669529663687f;
  __shared__ float s[NN];
  __shared__ float qs[DH];
  __shared__ float rbuf[256];
  __shared__ float part[8][33];
  if (tid < DH) qs[tid] = q[(long)b * BD + h * DH + tid];
  __syncthreads();
  long base = ((long)b * NN) * BD + h * DH;
  for (int k = tid; k < NN; k += 256) {
    float dot = 0.f;
    #pragma unroll
    for (int d = 0; d < DH; d++) dot += qs[d] * K[base + (long)k * BD + d];
    s[k] = dot * scale;
  }
  __syncthreads();
  float m = -1e30f;
  for (int k = tid; k < NN; k += 256) m = fmaxf(m, s[k]);
  rbuf[tid] = m;
  __syncthreads();
  for (int st = 128; st > 0; st >>= 1) {
    if (tid < st) rbuf[tid] = fmaxf(rbuf[tid], rbuf[tid + st]);
    __syncthreads();
  }
  float mx = rbuf[0];
  __syncthreads();
  float sm = 0.f;
  for (int k = tid; k < NN; k += 256) {
    float p = __expf(s[k] - mx);
    s[k] = p;
    sm += p;
  }
  rbuf[tid] = sm;
  __syncthreads();
  for (int st = 128; st > 0; st >>= 1) {
    if (tid < st) rbuf[tid] += rbuf[tid + st];
    __syncthreads();
  }
  float inv = 1.f / rbuf[0];
  int d = tid & 31, slice = tid >> 5;
  float acc = 0.f;
  for (int k = slice; k < NN; k += 8) acc += s[k] * V[base + (long)k * BD + d];
  part[slice][d] = acc;
  __syncthreads();
  if (tid < DH) {
    float ss = 0.f;
    #pragma unroll
    for (int t = 0; t < 8; t++) ss += part[t][tid];
    o[(long)b * BD + h * DH + tid] = ss * inv;
  }
}

// ---------------- relay row ops ----------------
__global__ __launch_bounds__(256) void rowvec_matmul(const float* __restrict__ X, long xstride,
                                                     const float* __restrict__ W,
                                                     float* __restrict__ out) {
  int b = blockIdx.x, tid = threadIdx.x;
  __shared__ float xs[BD];
  xs[tid] = X[(long)b * xstride + tid];
  __syncthreads();
  float acc = 0.f;
  for (int k = 0; k < BD; k++) acc += xs[k] * W[(long)k * BD + tid];
  out[(long)b * BD + tid] = acc;
}

__global__ __launch_bounds__(256) void rowvec_oproj_ln(const float* __restrict__ o,
                                                       const float* __restrict__ Wo,
                                                       const float* __restrict__ Xres, long xstride,
                                                       const float* __restrict__ g,
                                                       const float* __restrict__ beta,
                                                       float* __restrict__ dst, long dstride) {
  int b = blockIdx.x, tid = threadIdx.x;
  __shared__ float xs[BD];
  __shared__ float rs[256], rq[256];
  xs[tid] = o[(long)b * BD + tid];
  __syncthreads();
  float acc = 0.f;
  for (int k = 0; k < BD; k++) acc += xs[k] * Wo[(long)k * BD + tid];
  float v = acc + Xres[(long)b * xstride + tid];
  rs[tid] = v;
  rq[tid] = v * v;
  __syncthreads();
  for (int st = 128; st > 0; st >>= 1) {
    if (tid < st) { rs[tid] += rs[tid + st]; rq[tid] += rq[tid + st]; }
    __syncthreads();
  }
  float mu = rs[0] * (1.f / BD);
  float var = rq[0] * (1.f / BD) - mu * mu;
  float y = (v - mu) * rsqrtf(var + EPSV) * g[tid] + beta[tid];
  dst[(long)b * dstride + tid] = y;
}

__global__ __launch_bounds__(256) void ln_residual(const float* __restrict__ OP,
                                                   float* __restrict__ X,
                                                   const float* __restrict__ g,
                                                   const float* __restrict__ beta) {
  long r = blockIdx.x;
  int tid = threadIdx.x;
  __shared__ float rs[256], rq[256];
  float v = OP[r * BD + tid] + X[r * BD + tid];
  rs[tid] = v;
  rq[tid] = v * v;
  __syncthreads();
  for (int st = 128; st > 0; st >>= 1) {
    if (tid < st) { rs[tid] += rs[tid + st]; rq[tid] += rq[tid + st]; }
    __syncthreads();
  }
  float mu = rs[0] * (1.f / BD);
  float var = rq[0] * (1.f / BD) - mu * mu;
  X[r * BD + tid] = (v - mu) * rsqrtf(var + EPSV) * g[tid] + beta[tid];
}

// ---------------- launch ----------------
extern "C" void kernel_launch(void* const* d_in, const int* in_sizes, int n_in,
                              void* d_out, int out_size, void* d_ws, size_t ws_size,
                              hipStream_t stream) {
  const float* gv    = (const float*)d_in[0];
  const float* graph = (const float*)d_in[1];
  const float* Wq    = (const float*)d_in[2];
  const float* Wk    = (const float*)d_in[3];
  const float* Wv    = (const float*)d_in[4];
  const float* Wo    = (const float*)d_in[5];
  const float* lg    = (const float*)d_in[6];
  const float* lb    = (const float*)d_in[7];
  float* out = (float*)d_out;

  float* ws = (float*)d_ws;
  const long S = (long)NB * LQ * BD;  // 4,198,400
  float* X    = ws;
  float* Qb   = ws + S;
  float* Kb   = ws + 2 * S;
  float* Vb   = ws + 3 * S;
  float* Ob   = ws + 4 * S;
  float* qrel = ws + 5 * S;
  float* orel = qrel + (long)NB * BD;
  // bf16 views for self-attention Q/K/V (Kb holds Qh+Kh, Vb holds Vh)
  unsigned short* Qh = (unsigned short*)Kb;
  unsigned short* Kh = (unsigned short*)Kb + S;
  unsigned short* Vh = (unsigned short*)Vb;

  const long WSZ = (long)BD * BD;
  const long XST = (long)LQ * BD;
  dim3 blk(256);

  k_copy<<<dim3(2048), blk, 0, stream>>>(gv, X, S);

  // ---- layer 0: relay GAT ----
  rowvec_matmul<<<dim3(NB), blk, 0, stream>>>(X, XST, Wq + 0 * WSZ, qrel);
  gemm_aw<<<dim3(16, 4, NB), blk, 0, stream>>>(X + BD, Wk + 0 * WSZ, Kb, NN, XST, (long)NN * BD);
  gemm_aw<<<dim3(16, 4, NB), blk, 0, stream>>>(X + BD, Wv + 0 * WSZ, Vb, NN, XST, (long)NN * BD);
  attn_relay<<<dim3(NB, NH), blk, 0, stream>>>(qrel, Kb, Vb, orel);
  rowvec_oproj_ln<<<dim3(NB), blk, 0, stream>>>(orel, Wo + 0 * WSZ, X, XST,
                                                lg + 0 * BD, lb + 0 * BD, X, XST);

  // ---- sat mixing: sat = G^T @ sat ----
  gemm_gtx<<<dim3(16, 4, NB), blk, 0, stream>>>(graph, X, Qb);
  k_copy_sat_to_x<<<dim3(2048), blk, 0, stream>>>(Qb, X);

  // ---- layers 1,2: self GAT (MFMA attention) ----
  for (int l = 1; l <= 2; l++) {
    gemm_aw_h<<<dim3(257, 4, 1), blk, 0, stream>>>(X, Wq + l * WSZ, Qh, NB * LQ);
    gemm_aw_h<<<dim3(257, 4, 1), blk, 0, stream>>>(X, Wk + l * WSZ, Kh, NB * LQ);
    gemm_aw_h<<<dim3(257, 4, 1), blk, 0, stream>>>(X, Wv + l * WSZ, Vh, NB * LQ);
    attn_mfma<<<dim3(17, NH, NB), blk, 0, stream>>>(Qh, Kh, Vh, Ob);
    gemm_aw<<<dim3(257, 4, 1), blk, 0, stream>>>(Ob, Wo + l * WSZ, Qb, NB * LQ, 0, 0);
    ln_residual<<<dim3(NB * LQ), blk, 0, stream>>>(Qb, X, lg + l * BD, lb + l * BD);
  }

  // ---- sat_u output ----
  k_sat_out<<<dim3(2048), blk, 0, stream>>>(X, out + (long)NB * BD);

  // ---- layer 3: final relay GAT -> z ----
  rowvec_matmul<<<dim3(NB), blk, 0, stream>>>(X, XST, Wq + 3 * WSZ, qrel);
  gemm_aw<<<dim3(16, 4, NB), blk, 0, stream>>>(X + BD, Wk + 3 * WSZ, Kb, NN, XST, (long)NN * BD);
  gemm_aw<<<dim3(16, 4, NB), blk, 0, stream>>>(X + BD, Wv + 3 * WSZ, Vb, NN, XST, (long)NN * BD);
  attn_relay<<<dim3(NB, NH), blk, 0, stream>>>(qrel, Kb, Vb, orel);
  rowvec_oproj_ln<<<dim3(NB), blk, 0, stream>>>(orel, Wo + 3 * WSZ, X, XST,
                                                lg + 3 * BD, lb + 3 * BD, out, BD);
}

// Round 5
// 748.564 us; speedup vs baseline: 4.8829x; 1.8340x over previous
//
#include <hip/hip_runtime.h>
#include <hip/hip_bf16.h>
#include <math.h>

#define BD   256    // D
#define NH   8      // heads
#define DH   32     // head dim
#define NB   16     // batch
#define NN   1024   // N
#define LQ   1025   // N+1
#define EPSV 1e-5f

typedef unsigned short ushort_t;
typedef __attribute__((ext_vector_type(8))) short short8;
typedef __attribute__((ext_vector_type(4))) float f32x4;

static __device__ __forceinline__ ushort_t f2b(float x) {
  union { __hip_bfloat16 h; ushort_t u; } cv;
  cv.h = __float2bfloat16(x);
  return cv.u;
}
static __device__ __forceinline__ float b2f(ushort_t u) {
  union { float f; unsigned v; } c; c.v = ((unsigned)u) << 16; return c.f;
}

// ---------------- copy / cast helpers ----------------
__global__ void k_copy_cast(const float* __restrict__ in, float* __restrict__ X,
                            ushort_t* __restrict__ Xh, long n) {
  long stride = (long)gridDim.x * 256;
  for (long i = (long)blockIdx.x * 256 + threadIdx.x; i < n; i += stride) {
    float v = in[i];
    X[i] = v;
    Xh[i] = f2b(v);
  }
}

// snapshot sat region of Xh (strided) into dense dst [b][NN][256]
__global__ void k_snap_sat(const ushort_t* __restrict__ Xh, ushort_t* __restrict__ dst) {
  long n = (long)NB * NN * 128;  // uint count
  long stride = (long)gridDim.x * 256;
  const unsigned* src = (const unsigned*)Xh;
  unsigned* d = (unsigned*)dst;
  for (long i = (long)blockIdx.x * 256 + threadIdx.x; i < n; i += stride) {
    long b = i / ((long)NN * 128);
    long r = i - b * ((long)NN * 128);
    d[i] = src[b * (long)LQ * 128 + 128 + r];
  }
}

__global__ void k_sat_out(const float* __restrict__ X, float* __restrict__ out) {
  long n = (long)NB * NN * BD;
  long stride = (long)gridDim.x * 256;
  for (long i = (long)blockIdx.x * 256 + threadIdx.x; i < n; i += stride) {
    long b = i / ((long)NN * BD);
    long r = i - b * ((long)NN * BD);
    out[i] = X[b * (long)LQ * BD + BD + r];
  }
}

// ---------------- weight transpose+cast: Wt[slot][n][k] = bf16(W[k][n]) ----------------
__global__ __launch_bounds__(256) void k_wtrans(const float* __restrict__ Wq,
                                                const float* __restrict__ Wk,
                                                const float* __restrict__ Wv,
                                                const float* __restrict__ Wo,
                                                ushort_t* __restrict__ Wt) {
  int mat = blockIdx.y;              // 0..15: type*4 + layer
  int type = mat >> 2, layer = mat & 3;
  const float* src = (type == 0) ? Wq : (type == 1) ? Wk : (type == 2) ? Wv : Wo;
  src += (long)layer * BD * BD;
  ushort_t* dst = Wt + (long)mat * BD * BD;
  __shared__ float t[32][33];
  int k0 = (blockIdx.x & 7) * 32, n0 = (blockIdx.x >> 3) * 32;
  int tid = threadIdx.x;
  for (int i = tid; i < 1024; i += 256) {
    int kk = i >> 5, nn = i & 31;
    t[kk][nn] = src[(long)(k0 + kk) * BD + n0 + nn];
  }
  __syncthreads();
  for (int i = tid; i < 1024; i += 256) {
    int nn = i >> 5, kk = i & 31;
    dst[(long)(n0 + nn) * BD + k0 + kk] = f2b(t[kk][nn]);
  }
}

// ---------------- MFMA GEMM: C[M,256] = Xh[M,256(bf16)] @ W (Wt[n][k] bf16) ----------------
// grid (ceil(M/64), 4, Z); block 256 = 4 waves, wave -> 16 rows x 64 cols.
__global__ __launch_bounds__(256) void gemm_xw(const ushort_t* __restrict__ Xh, long strideX,
                                               const ushort_t* __restrict__ Wt,
                                               float* __restrict__ Cf, ushort_t* __restrict__ Ch,
                                               long strideC, int M) {
  Xh += (long)blockIdx.z * strideX;
  __shared__ __align__(16) ushort_t Ws[64 * 264];  // [n][k], +8 pad
  int tid = threadIdx.x;
  int wave = tid >> 6, lane = tid & 63;
  int l15 = lane & 15, quad = lane >> 4;
  int m0 = blockIdx.x * 64, n0 = blockIdx.y * 64;
  for (int i = tid; i < 64 * 32; i += 256) {
    int r = i >> 5, c8 = (i & 31) * 8;
    *(uint4*)&Ws[r * 264 + c8] = *(const uint4*)&Wt[(long)(n0 + r) * 256 + c8];
  }
  __syncthreads();
  int mrow = m0 + wave * 16 + l15;
  if (mrow > M - 1) mrow = M - 1;
  f32x4 acc[4];
  #pragma unroll
  for (int f = 0; f < 4; f++) { acc[f][0] = 0.f; acc[f][1] = 0.f; acc[f][2] = 0.f; acc[f][3] = 0.f; }
  #pragma unroll
  for (int k0 = 0; k0 < 256; k0 += 32) {
    short8 a = *(const short8*)&Xh[(long)mrow * 256 + k0 + quad * 8];
    #pragma unroll
    for (int f = 0; f < 4; f++) {
      short8 bb = *(const short8*)&Ws[(f * 16 + l15) * 264 + k0 + quad * 8];
      acc[f] = __builtin_amdgcn_mfma_f32_16x16x32_bf16(a, bb, acc[f], 0, 0, 0);
    }
  }
  long cb = (long)blockIdx.z * strideC;
  #pragma unroll
  for (int f = 0; f < 4; f++)
    #pragma unroll
    for (int r = 0; r < 4; r++) {
      int m = m0 + wave * 16 + quad * 4 + r;
      if (m < M) {
        long idx = cb + (long)m * 256 + n0 + f * 16 + l15;
        if (Cf) Cf[idx] = acc[f][r];
        else    Ch[idx] = f2b(acc[f][r]);
      }
    }
}

// ---------------- graph mixing via MFMA: C[b,m,d] = sum_n G[b,n,m] * sat[b,n,d] ----------------
// grid (16, 4, 16); in-LDS transpose of G (fp32->bf16) and satSrc (dense bf16 snapshot).
// Writes X (fp32) and Xh (bf16) sat rows.
__global__ __launch_bounds__(256) void gemm_gtx(const float* __restrict__ G,
                                                const ushort_t* __restrict__ satSrc,
                                                float* __restrict__ X,
                                                ushort_t* __restrict__ XhO) {
  int b = blockIdx.z;
  const float* Gb = G + (long)b * NN * NN;
  const ushort_t* Sb = satSrc + (long)b * NN * 256;
  __shared__ __align__(16) ushort_t Gs[64][72];  // [m][n]
  __shared__ __align__(16) ushort_t Xs[64][72];  // [d][n]
  int tid = threadIdx.x;
  int wave = tid >> 6, lane = tid & 63;
  int l15 = lane & 15, quad = lane >> 4;
  int m0 = blockIdx.x * 64, d0 = blockIdx.y * 64;
  f32x4 acc[4];
  #pragma unroll
  for (int f = 0; f < 4; f++) { acc[f][0] = 0.f; acc[f][1] = 0.f; acc[f][2] = 0.f; acc[f][3] = 0.f; }
  for (int n0 = 0; n0 < NN; n0 += 64) {
    for (int i = tid; i < 2048; i += 256) {
      int n = i >> 5, m2 = (i & 31) * 2;
      float2 g = *(const float2*)&Gb[(long)(n0 + n) * NN + m0 + m2];
      Gs[m2][n] = f2b(g.x); Gs[m2 + 1][n] = f2b(g.y);
    }
    for (int i = tid; i < 2048; i += 256) {
      int n = i >> 5, d2 = (i & 31) * 2;
      unsigned w = *(const unsigned*)&Sb[(long)(n0 + n) * 256 + d0 + d2];
      Xs[d2][n] = (ushort_t)(w & 0xffff); Xs[d2 + 1][n] = (ushort_t)(w >> 16);
    }
    __syncthreads();
    #pragma unroll
    for (int ns = 0; ns < 2; ns++) {
      short8 a = *(const short8*)&Gs[wave * 16 + l15][ns * 32 + quad * 8];
      #pragma unroll
      for (int f = 0; f < 4; f++) {
        short8 bb = *(const short8*)&Xs[f * 16 + l15][ns * 32 + quad * 8];
        acc[f] = __builtin_amdgcn_mfma_f32_16x16x32_bf16(a, bb, acc[f], 0, 0, 0);
      }
    }
    __syncthreads();
  }
  long xb = ((long)b * LQ + 1) * 256;
  #pragma unroll
  for (int f = 0; f < 4; f++)
    #pragma unroll
    for (int r = 0; r < 4; r++) {
      int m = m0 + wave * 16 + quad * 4 + r;
      int d = d0 + f * 16 + l15;
      long idx = xb + (long)m * 256 + d;
      X[idx] = acc[f][r];
      XhO[idx] = f2b(acc[f][r]);
    }
}

// ---------------- self attention via MFMA, bf16 in/out, online-max softmax ----------------
__global__ __launch_bounds__(256) void attn_mfma(const ushort_t* __restrict__ Qh,
                                                 const ushort_t* __restrict__ Kh,
                                                 const ushort_t* __restrict__ Vh,
                                                 ushort_t* __restrict__ Oh) {
  __shared__ __align__(16) ushort_t Ks[32][40];
  __shared__ __align__(16) ushort_t Vt[32][40];
  __shared__ __align__(16) ushort_t Ps[4][16][40];
  const float scale = 0.17677669529663687f;  // 1/sqrt(32)
  int tid = threadIdx.x;
  int wave = tid >> 6, lane = tid & 63;
  int l15 = lane & 15, quad = lane >> 4;
  int h = blockIdx.y, b = blockIdx.z;
  long hb = ((long)b * LQ) * BD + h * DH;
  int q0 = blockIdx.x * 64 + wave * 16;
  int qc = q0 + l15; if (qc > LQ - 1) qc = LQ - 1;
  short8 qfrag = *(const short8*)&Qh[hb + (long)qc * BD + quad * 8];

  f32x4 o0, o1, lsum, mrun;
  #pragma unroll
  for (int r = 0; r < 4; r++) { o0[r] = 0.f; o1[r] = 0.f; lsum[r] = 0.f; mrun[r] = -1e30f; }

  int sr = tid >> 3;
  int sd = (tid & 7) * 4;

  for (int k0 = 0; k0 < LQ; k0 += 32) {
    int kk = k0 + sr;
    if (kk < LQ) {
      *(uint2*)&Ks[sr][sd] = *(const uint2*)&Kh[hb + (long)kk * BD + sd];
      const ushort_t* vp = &Vh[hb + (long)kk * BD + sd];
      Vt[sd][sr] = vp[0]; Vt[sd + 1][sr] = vp[1];
      Vt[sd + 2][sr] = vp[2]; Vt[sd + 3][sr] = vp[3];
    } else {
      uint2 z; z.x = 0; z.y = 0;
      *(uint2*)&Ks[sr][sd] = z;
      Vt[sd][sr] = 0; Vt[sd + 1][sr] = 0; Vt[sd + 2][sr] = 0; Vt[sd + 3][sr] = 0;
    }
    __syncthreads();
    short8 bk0 = *(const short8*)&Ks[l15][quad * 8];
    short8 bk1 = *(const short8*)&Ks[16 + l15][quad * 8];
    f32x4 z4; z4[0] = 0.f; z4[1] = 0.f; z4[2] = 0.f; z4[3] = 0.f;
    f32x4 s0 = __builtin_amdgcn_mfma_f32_16x16x32_bf16(qfrag, bk0, z4, 0, 0, 0);
    f32x4 s1 = __builtin_amdgcn_mfma_f32_16x16x32_bf16(qfrag, bk1, z4, 0, 0, 0);
    bool v0 = (k0 + l15) < LQ;
    bool v1 = (k0 + 16 + l15) < LQ;
    #pragma unroll
    for (int r = 0; r < 4; r++) {
      float sc0 = v0 ? s0[r] * scale : -1e30f;
      float sc1 = v1 ? s1[r] * scale : -1e30f;
      float cm = fmaxf(sc0, sc1);
      cm = fmaxf(cm, __shfl_xor(cm, 1));
      cm = fmaxf(cm, __shfl_xor(cm, 2));
      cm = fmaxf(cm, __shfl_xor(cm, 4));
      cm = fmaxf(cm, __shfl_xor(cm, 8));
      float mn = fmaxf(mrun[r], cm);
      float alpha = __expf(mrun[r] - mn);
      mrun[r] = mn;
      float p0 = __expf(sc0 - mn);
      float p1 = __expf(sc1 - mn);
      lsum[r] = lsum[r] * alpha + p0 + p1;
      o0[r] *= alpha; o1[r] *= alpha;
      Ps[wave][quad * 4 + r][l15] = f2b(p0);
      Ps[wave][quad * 4 + r][16 + l15] = f2b(p1);
    }
    short8 pf  = *(const short8*)&Ps[wave][l15][quad * 8];
    short8 vf0 = *(const short8*)&Vt[l15][quad * 8];
    short8 vf1 = *(const short8*)&Vt[16 + l15][quad * 8];
    o0 = __builtin_amdgcn_mfma_f32_16x16x32_bf16(pf, vf0, o0, 0, 0, 0);
    o1 = __builtin_amdgcn_mfma_f32_16x16x32_bf16(pf, vf1, o1, 0, 0, 0);
    __syncthreads();
  }
  #pragma unroll
  for (int r = 0; r < 4; r++) {
    float s = lsum[r];
    s += __shfl_xor(s, 1); s += __shfl_xor(s, 2);
    s += __shfl_xor(s, 4); s += __shfl_xor(s, 8);
    lsum[r] = s;
  }
  #pragma unroll
  for (int r = 0; r < 4; r++) {
    int row = q0 + quad * 4 + r;
    if (row < LQ) {
      float inv = 1.f / lsum[r];
      Oh[hb + (long)row * BD + l15] = f2b(o0[r] * inv);
      Oh[hb + (long)row * BD + 16 + l15] = f2b(o1[r] * inv);
    }
  }
}

// ---------------- relay attention: Lq=1, Lk=1024, bf16 K/V ----------------
__global__ __launch_bounds__(256) void attn_relay(const float* __restrict__ q,
                                                  const ushort_t* __restrict__ K,
                                                  const ushort_t* __restrict__ V,
                                                  float* __restrict__ o) {
  int b = blockIdx.x, h = blockIdx.y;
  int tid = threadIdx.x;
  const float scale = 0.17677669529663687f;
  __shared__ float s[NN];
  __shared__ float qs[DH];
  __shared__ float rbuf[256];
  __shared__ float part[8][33];
  if (tid < DH) qs[tid] = q[(long)b * BD + h * DH + tid];
  __syncthreads();
  long base = ((long)b * NN) * BD + h * DH;
  for (int k = tid; k < NN; k += 256) {
    float dot = 0.f;
    const ushort_t* kr = &K[base + (long)k * BD];
    #pragma unroll
    for (int d2 = 0; d2 < 16; d2++) {
      unsigned w = *(const unsigned*)&kr[d2 * 2];
      dot += qs[d2 * 2] * b2f((ushort_t)(w & 0xffff)) + qs[d2 * 2 + 1] * b2f((ushort_t)(w >> 16));
    }
    s[k] = dot * scale;
  }
  __syncthreads();
  float m = -1e30f;
  for (int k = tid; k < NN; k += 256) m = fmaxf(m, s[k]);
  rbuf[tid] = m;
  __syncthreads();
  for (int st = 128; st > 0; st >>= 1) {
    if (tid < st) rbuf[tid] = fmaxf(rbuf[tid], rbuf[tid + st]);
    __syncthreads();
  }
  float mx = rbuf[0];
  __syncthreads();
  float sm = 0.f;
  for (int k = tid; k < NN; k += 256) {
    float p = __expf(s[k] - mx);
    s[k] = p;
    sm += p;
  }
  rbuf[tid] = sm;
  __syncthreads();
  for (int st = 128; st > 0; st >>= 1) {
    if (tid < st) rbuf[tid] += rbuf[tid + st];
    __syncthreads();
  }
  float inv = 1.f / rbuf[0];
  int d = tid & 31, slice = tid >> 5;
  float acc = 0.f;
  for (int k = slice; k < NN; k += 8) acc += s[k] * b2f(V[base + (long)k * BD + d]);
  part[slice][d] = acc;
  __syncthreads();
  if (tid < DH) {
    float ss = 0.f;
    #pragma unroll
    for (int t = 0; t < 8; t++) ss += part[t][tid];
    o[(long)b * BD + h * DH + tid] = ss * inv;
  }
}

// ---------------- relay row ops (fp32 weights for precision; tiny) ----------------
__global__ __launch_bounds__(256) void rowvec_matmul(const float* __restrict__ X, long xstride,
                                                     const float* __restrict__ W,
                                                     float* __restrict__ out) {
  int b = blockIdx.x, tid = threadIdx.x;
  __shared__ float xs[BD];
  xs[tid] = X[(long)b * xstride + tid];
  __syncthreads();
  float acc = 0.f;
  for (int k = 0; k < BD; k++) acc += xs[k] * W[(long)k * BD + tid];
  out[(long)b * BD + tid] = acc;
}

__global__ __launch_bounds__(256) void rowvec_oproj_ln(const float* __restrict__ o,
                                                       const float* __restrict__ Wo,
                                                       const float* __restrict__ Xres, long xstride,
                                                       const float* __restrict__ g,
                                                       const float* __restrict__ beta,
                                                       float* __restrict__ dst, long dstride,
                                                       ushort_t* __restrict__ dsth, long dhstride) {
  int b = blockIdx.x, tid = threadIdx.x;
  __shared__ float xs[BD];
  __shared__ float rs[256], rq[256];
  xs[tid] = o[(long)b * BD + tid];
  __syncthreads();
  float acc = 0.f;
  for (int k = 0; k < BD; k++) acc += xs[k] * Wo[(long)k * BD + tid];
  float v = acc + Xres[(long)b * xstride + tid];
  rs[tid] = v;
  rq[tid] = v * v;
  __syncthreads();
  for (int st = 128; st > 0; st >>= 1) {
    if (tid < st) { rs[tid] += rs[tid + st]; rq[tid] += rq[tid + st]; }
    __syncthreads();
  }
  float mu = rs[0] * (1.f / BD);
  float var = rq[0] * (1.f / BD) - mu * mu;
  float y = (v - mu) * rsqrtf(var + EPSV) * g[tid] + beta[tid];
  dst[(long)b * dstride + tid] = y;
  if (dsth) dsth[(long)b * dhstride + tid] = f2b(y);
}

__global__ __launch_bounds__(256) void ln_residual(const float* __restrict__ OP,
                                                   float* __restrict__ X,
                                                   ushort_t* __restrict__ Xh,
                                                   const float* __restrict__ g,
                                                   const float* __restrict__ beta) {
  long r = blockIdx.x;
  int tid = threadIdx.x;
  __shared__ float rs[256], rq[256];
  float v = OP[r * BD + tid] + X[r * BD + tid];
  rs[tid] = v;
  rq[tid] = v * v;
  __syncthreads();
  for (int st = 128; st > 0; st >>= 1) {
    if (tid < st) { rs[tid] += rs[tid + st]; rq[tid] += rq[tid + st]; }
    __syncthreads();
  }
  float mu = rs[0] * (1.f / BD);
  float var = rq[0] * (1.f / BD) - mu * mu;
  float y = (v - mu) * rsqrtf(var + EPSV) * g[tid] + beta[tid];
  X[r * BD + tid] = y;
  Xh[r * BD + tid] = f2b(y);
}

// ---------------- launch ----------------
extern "C" void kernel_launch(void* const* d_in, const int* in_sizes, int n_in,
                              void* d_out, int out_size, void* d_ws, size_t ws_size,
                              hipStream_t stream) {
  const float* gv    = (const float*)d_in[0];
  const float* graph = (const float*)d_in[1];
  const float* Wq    = (const float*)d_in[2];
  const float* Wk    = (const float*)d_in[3];
  const float* Wv    = (const float*)d_in[4];
  const float* Wo    = (const float*)d_in[5];
  const float* lg    = (const float*)d_in[6];
  const float* lb    = (const float*)d_in[7];
  float* out = (float*)d_out;

  const long S = (long)NB * LQ * BD;  // 4,198,400 elements
  char* base = (char*)d_ws;
  float*    X    = (float*)base;                       // S*4
  float*    B1   = (float*)(base + S * 4);             // S*4   (OP fp32)
  ushort_t* Xh   = (ushort_t*)(base + S * 8);          // S*2
  ushort_t* Qh   = (ushort_t*)(base + S * 10);         // S*2
  ushort_t* Kh   = (ushort_t*)(base + S * 12);         // S*2   (also relay K dense)
  ushort_t* Vh   = (ushort_t*)(base + S * 14);         // S*2   (also relay V dense)
  ushort_t* Oh   = (ushort_t*)(base + S * 16);         // S*2   (also gtx sat snapshot)
  ushort_t* Wt   = (ushort_t*)(base + S * 18);         // 16*65536*2 = 2MB
  float*    qrel = (float*)(base + S * 18 + 16L * 65536 * 2);
  float*    orel = qrel + (long)NB * BD;

  const long WSZ = (long)BD * BD;
  const long XST = (long)LQ * BD;
  const long RST = (long)NN * BD;   // relay K/V dense batch stride
  dim3 blk(256);

  // X, Xh = graph_vectors
  k_copy_cast<<<dim3(2048), blk, 0, stream>>>(gv, X, Xh, S);
  // Wt[type*4+layer][n][k]
  k_wtrans<<<dim3(64, 16), blk, 0, stream>>>(Wq, Wk, Wv, Wo, Wt);

  // ---- layer 0: relay GAT ----
  rowvec_matmul<<<dim3(NB), blk, 0, stream>>>(X, XST, Wq + 0 * WSZ, qrel);
  gemm_xw<<<dim3(16, 4, NB), blk, 0, stream>>>(Xh + BD, XST, Wt + (1 * 4 + 0) * WSZ,
                                               nullptr, Kh, RST, NN);
  gemm_xw<<<dim3(16, 4, NB), blk, 0, stream>>>(Xh + BD, XST, Wt + (2 * 4 + 0) * WSZ,
                                               nullptr, Vh, RST, NN);
  attn_relay<<<dim3(NB, NH), blk, 0, stream>>>(qrel, Kh, Vh, orel);
  rowvec_oproj_ln<<<dim3(NB), blk, 0, stream>>>(orel, Wo + 0 * WSZ, X, XST,
                                                lg + 0 * BD, lb + 0 * BD, X, XST, Xh, XST);

  // ---- sat mixing: sat = G^T @ sat (MFMA) ----
  k_snap_sat<<<dim3(2048), blk, 0, stream>>>(Xh, Oh);
  gemm_gtx<<<dim3(16, 4, NB), blk, 0, stream>>>(graph, Oh, X, Xh);

  // ---- layers 1,2: self GAT ----
  for (int l = 1; l <= 2; l++) {
    gemm_xw<<<dim3(257, 4, 1), blk, 0, stream>>>(Xh, 0, Wt + (0 * 4 + l) * WSZ,
                                                 nullptr, Qh, 0, NB * LQ);
    gemm_xw<<<dim3(257, 4, 1), blk, 0, stream>>>(Xh, 0, Wt + (1 * 4 + l) * WSZ,
                                                 nullptr, Kh, 0, NB * LQ);
    gemm_xw<<<dim3(257, 4, 1), blk, 0, stream>>>(Xh, 0, Wt + (2 * 4 + l) * WSZ,
                                                 nullptr, Vh, 0, NB * LQ);
    attn_mfma<<<dim3(17, NH, NB), blk, 0, stream>>>(Qh, Kh, Vh, Oh);
    gemm_xw<<<dim3(257, 4, 1), blk, 0, stream>>>(Oh, 0, Wt + (3 * 4 + l) * WSZ,
                                                 B1, nullptr, 0, NB * LQ);
    ln_residual<<<dim3(NB * LQ), blk, 0, stream>>>(B1, X, Xh, lg + l * BD, lb + l * BD);
  }

  // ---- sat_u output ----
  k_sat_out<<<dim3(2048), blk, 0, stream>>>(X, out + (long)NB * BD);

  // ---- layer 3: final relay GAT -> z ----
  rowvec_matmul<<<dim3(NB), blk, 0, stream>>>(X, XST, Wq + 3 * WSZ, qrel);
  gemm_xw<<<dim3(16, 4, NB), blk, 0, stream>>>(Xh + BD, XST, Wt + (1 * 4 + 3) * WSZ,
                                               nullptr, Kh, RST, NN);
  gemm_xw<<<dim3(16, 4, NB), blk, 0, stream>>>(Xh + BD, XST, Wt + (2 * 4 + 3) * WSZ,
                                               nullptr, Vh, RST, NN);
  attn_relay<<<dim3(NB, NH), blk, 0, stream>>>(qrel, Kh, Vh, orel);
  rowvec_oproj_ln<<<dim3(NB), blk, 0, stream>>>(orel, Wo + 3 * WSZ, X, XST,
                                                lg + 3 * BD, lb + 3 * BD, out, BD, nullptr, 0);
}